// Round 1
// baseline (1238.206 us; speedup 1.0000x reference)
//
#include <hip/hip_runtime.h>
#include <cstdint>
#include <cstddef>

// Problem constants (from reference setup_inputs)
#define FDIM 1024   // feature dim F
#define DDIM 128    // fc out dim D
#define NGRAPH 64   // num graphs B

// ---------------------------------------------------------------------------
// init: deg=1 (self-loop), cnt=0, pool=0
// ---------------------------------------------------------------------------
__global__ void k_init(int* deg1, int* deg2, int* cnt1, int* cnt2,
                       float* pool1, float* pool2, int N) {
  int i = blockIdx.x * blockDim.x + threadIdx.x;
  if (i < N) { deg1[i] = 1; deg2[i] = 1; }
  if (i < NGRAPH) { cnt1[i] = 0; cnt2[i] = 0; }
  if (i < NGRAPH * FDIM) { pool1[i] = 0.f; pool2[i] = 0.f; }
}

// ---------------------------------------------------------------------------
// prep: in-degree count (dst row of edge_index) + nodes-per-graph count
// ---------------------------------------------------------------------------
__global__ void k_prep(const int* __restrict__ ei, int* deg,
                       const int* __restrict__ batch, int* cnt, int E, int N) {
  int i = blockIdx.x * blockDim.x + threadIdx.x;
  if (i < E) atomicAdd(&deg[ei[E + i]], 1);   // ei[E..2E) = dst row
  if (i < N) atomicAdd(&cnt[batch[i]], 1);
}

// ---------------------------------------------------------------------------
// scan: single-block exclusive prefix sum of deg -> off, cur; dinv = rsqrt(deg)
// ---------------------------------------------------------------------------
#define SCAN_T 1024
#define SCAN_PER 16   // covers N <= 16384
__global__ __launch_bounds__(SCAN_T) void k_scan(const int* __restrict__ deg,
                                                 int* off, int* cur, float* dinv, int n) {
  __shared__ int sums[SCAN_T];
  int t = threadIdx.x;
  int base = t * SCAN_PER;
  int local[SCAN_PER];
  int s = 0;
  #pragma unroll
  for (int i = 0; i < SCAN_PER; ++i) {
    int idx = base + i;
    int d = (idx < n) ? deg[idx] : 0;
    local[i] = s;
    s += d;
    if (idx < n) dinv[idx] = rsqrtf((float)d);  // deg >= 1 always (self-loop)
  }
  sums[t] = s;
  __syncthreads();
  // Hillis-Steele inclusive scan
  for (int o = 1; o < SCAN_T; o <<= 1) {
    int v = (t >= o) ? sums[t - o] : 0;
    __syncthreads();
    sums[t] += v;
    __syncthreads();
  }
  int basesum = (t > 0) ? sums[t - 1] : 0;
  #pragma unroll
  for (int i = 0; i < SCAN_PER; ++i) {
    int idx = base + i;
    if (idx < n) { int o = basesum + local[i]; off[idx] = o; cur[idx] = o; }
  }
  if (t == SCAN_T - 1) off[n] = sums[SCAN_T - 1];
}

// ---------------------------------------------------------------------------
// fill: scatter edges + self-loops into CSR (adjsrc, adjw = dinv[s]*dinv[d])
// ---------------------------------------------------------------------------
__global__ void k_fill(const int* __restrict__ ei, int* cur,
                       const float* __restrict__ dinv,
                       int* adjsrc, float* adjw, int E, int N) {
  int i = blockIdx.x * blockDim.x + threadIdx.x;
  if (i < E) {
    int s = ei[i];        // src row
    int d = ei[E + i];    // dst row
    int p = atomicAdd(&cur[d], 1);
    adjsrc[p] = s;
    adjw[p] = dinv[s] * dinv[d];
  }
  if (i < N) {
    int p = atomicAdd(&cur[i], 1);
    adjsrc[p] = i;
    adjw[p] = dinv[i] * dinv[i];
  }
}

// ---------------------------------------------------------------------------
// GEMM: h[M,1024] = x[M,1024] @ W[1024,1024]   (fp32, tiled 64x64, 4x4/thread)
// ---------------------------------------------------------------------------
#define BM 64
#define BN 64
#define BK 16
__global__ __launch_bounds__(256) void k_gemm(const float* __restrict__ A,
                                              const float* __restrict__ B,
                                              float* __restrict__ C, int M) {
  const int K = FDIM, N = FDIM;
  __shared__ float As[BK][BM + 4];
  __shared__ float Bs[BK][BN];
  int nb = N / BN;                 // 16
  int bx = blockIdx.x % nb;
  int by = blockIdx.x / nb;
  int m0 = by * BM, n0 = bx * BN;
  int t = threadIdx.x;
  int tx = t % 16, ty = t / 16;
  int arow = t / 4, acg = t % 4;   // A loader: 64 rows x 4 float4-groups
  int brow = t / 16, bcg = t % 16; // B loader: 16 rows x 16 float4-groups
  float acc[4][4] = {};
  for (int k0 = 0; k0 < K; k0 += BK) {
    float4 a4 = make_float4(0.f, 0.f, 0.f, 0.f);
    int am = m0 + arow;
    if (am < M) a4 = *(const float4*)(A + (size_t)am * K + k0 + acg * 4);
    As[acg * 4 + 0][arow] = a4.x;
    As[acg * 4 + 1][arow] = a4.y;
    As[acg * 4 + 2][arow] = a4.z;
    As[acg * 4 + 3][arow] = a4.w;
    float4 b4 = *(const float4*)(B + (size_t)(k0 + brow) * N + n0 + bcg * 4);
    *(float4*)&Bs[brow][bcg * 4] = b4;
    __syncthreads();
    #pragma unroll
    for (int k = 0; k < BK; ++k) {
      float a[4], b[4];
      *(float4*)a = *(const float4*)&As[k][ty * 4];
      *(float4*)b = *(const float4*)&Bs[k][tx * 4];
      #pragma unroll
      for (int i = 0; i < 4; ++i)
        #pragma unroll
        for (int j = 0; j < 4; ++j) acc[i][j] += a[i] * b[j];
    }
    __syncthreads();
  }
  #pragma unroll
  for (int i = 0; i < 4; ++i) {
    int m = m0 + ty * 4 + i;
    if (m < M) *(float4*)(C + (size_t)m * N + n0 + tx * 4) = *(float4*)&acc[i][0];
  }
}

// ---------------------------------------------------------------------------
// aggregate + bias + LeakyReLU + mean-pool (atomic into pool[64,1024])
// one block (256 threads, float4 each) per dst node
// ---------------------------------------------------------------------------
__global__ __launch_bounds__(256) void k_agg_pool(const float* __restrict__ h,
                                                  const int* __restrict__ off,
                                                  const int* __restrict__ adjsrc,
                                                  const float* __restrict__ adjw,
                                                  const float* __restrict__ bias,
                                                  const int* __restrict__ batch,
                                                  const int* __restrict__ cnt,
                                                  float* pool) {
  int v = blockIdx.x;
  int t = threadIdx.x;          // 0..255, covers 1024 floats as float4
  int pb = off[v], pe = off[v + 1];
  float4 acc = make_float4(0.f, 0.f, 0.f, 0.f);
  for (int p = pb; p < pe; ++p) {
    int s = adjsrc[p];
    float w = adjw[p];
    float4 hv = ((const float4*)(h + (size_t)s * FDIM))[t];
    acc.x += w * hv.x; acc.y += w * hv.y; acc.z += w * hv.z; acc.w += w * hv.w;
  }
  float4 b4 = ((const float4*)bias)[t];
  int g = batch[v];
  float ic = 1.0f / fmaxf((float)cnt[g], 1.0f);
  float vx = acc.x + b4.x; vx = (vx >= 0.f) ? vx : 0.01f * vx;
  float vy = acc.y + b4.y; vy = (vy >= 0.f) ? vy : 0.01f * vy;
  float vz = acc.z + b4.z; vz = (vz >= 0.f) ? vz : 0.01f * vz;
  float vw = acc.w + b4.w; vw = (vw >= 0.f) ? vw : 0.01f * vw;
  float* pg = pool + (size_t)g * FDIM + t * 4;
  atomicAdd(pg + 0, vx * ic);
  atomicAdd(pg + 1, vy * ic);
  atomicAdd(pg + 2, vz * ic);
  atomicAdd(pg + 3, vw * ic);
}

// ---------------------------------------------------------------------------
// fc: out[64,128] = leaky(pool[64,1024] @ W[1024,128] + b)
// ---------------------------------------------------------------------------
__global__ __launch_bounds__(DDIM) void k_fc(const float* __restrict__ pool,
                                             const float* __restrict__ W,
                                             const float* __restrict__ b,
                                             float* __restrict__ out) {
  int g = blockIdx.x;
  int j = threadIdx.x;   // 0..127
  __shared__ float xs[FDIM];
  for (int k = j; k < FDIM; k += DDIM) xs[k] = pool[(size_t)g * FDIM + k];
  __syncthreads();
  float acc = b[j];
  for (int k = 0; k < FDIM; ++k) acc += xs[k] * W[(size_t)k * DDIM + j];
  out[g * DDIM + j] = (acc >= 0.f) ? acc : 0.01f * acc;
}

// ---------------------------------------------------------------------------
// final: out[g] = concat(o1,o2) @ finalW + finalb
// ---------------------------------------------------------------------------
__global__ __launch_bounds__(DDIM) void k_final(const float* __restrict__ o1,
                                                const float* __restrict__ o2,
                                                const float* __restrict__ W,
                                                const float* __restrict__ b,
                                                float* __restrict__ out) {
  int g = blockIdx.x;
  int t = threadIdx.x;  // 0..127 (2 waves)
  float acc = o1[g * DDIM + t] * W[t] + o2[g * DDIM + t] * W[DDIM + t];
  #pragma unroll
  for (int o = 32; o > 0; o >>= 1) acc += __shfl_down(acc, o);
  __shared__ float ws2[2];
  if ((t & 63) == 0) ws2[t >> 6] = acc;
  __syncthreads();
  if (t == 0) out[g] = ws2[0] + ws2[1] + b[0];
}

// ---------------------------------------------------------------------------
extern "C" void kernel_launch(void* const* d_in, const int* in_sizes, int n_in,
                              void* d_out, int out_size, void* d_ws, size_t ws_size,
                              hipStream_t stream) {
  const float* x1 = (const float*)d_in[0];
  const int* ei1 = (const int*)d_in[1];
  const int* batch1 = (const int*)d_in[2];
  const float* x2 = (const float*)d_in[3];
  const int* ei2 = (const int*)d_in[4];
  const int* batch2 = (const int*)d_in[5];
  // d_in[6..9] = mas scalars, unused
  const float* conv1_W = (const float*)d_in[10];
  const float* conv1_b = (const float*)d_in[11];
  const float* fc1_W = (const float*)d_in[12];
  const float* fc1_b = (const float*)d_in[13];
  const float* conv2_W = (const float*)d_in[14];
  const float* conv2_b = (const float*)d_in[15];
  const float* fc2_W = (const float*)d_in[16];
  const float* fc2_b = (const float*)d_in[17];
  const float* final_W = (const float*)d_in[18];
  const float* final_b = (const float*)d_in[19];
  float* out = (float*)d_out;

  const int N = in_sizes[2];        // 10000
  const int E = in_sizes[1] / 2;    // 80000
  const int A = E + N;              // adjacency entries incl. self-loops

  // workspace carve-up
  size_t off_b = 0;
  auto alloc = [&](size_t bytes) -> void* {
    void* p = (char*)d_ws + off_b;
    off_b += (bytes + 255) & ~(size_t)255;
    return p;
  };
  float* h = (float*)alloc((size_t)N * FDIM * 4);   // shared between branches (sequential)
  int* deg1 = (int*)alloc(N * 4);
  int* deg2 = (int*)alloc(N * 4);
  int* cnt1 = (int*)alloc(NGRAPH * 4);
  int* cnt2 = (int*)alloc(NGRAPH * 4);
  int* off1 = (int*)alloc((N + 1) * 4);
  int* off2 = (int*)alloc((N + 1) * 4);
  int* cur1 = (int*)alloc(N * 4);
  int* cur2 = (int*)alloc(N * 4);
  float* dinv1 = (float*)alloc(N * 4);
  float* dinv2 = (float*)alloc(N * 4);
  int* adjsrc1 = (int*)alloc((size_t)A * 4);
  int* adjsrc2 = (int*)alloc((size_t)A * 4);
  float* adjw1 = (float*)alloc((size_t)A * 4);
  float* adjw2 = (float*)alloc((size_t)A * 4);
  float* pool1 = (float*)alloc(NGRAPH * FDIM * 4);
  float* pool2 = (float*)alloc(NGRAPH * FDIM * 4);
  float* fco1 = (float*)alloc(NGRAPH * DDIM * 4);
  float* fco2 = (float*)alloc(NGRAPH * DDIM * 4);

  const int T = 256;
  // init
  k_init<<<(NGRAPH * FDIM + T - 1) / T, T, 0, stream>>>(deg1, deg2, cnt1, cnt2, pool1, pool2, N);
  // degree + graph-size counts
  int gE = (E + T - 1) / T;
  k_prep<<<gE, T, 0, stream>>>(ei1, deg1, batch1, cnt1, E, N);
  k_prep<<<gE, T, 0, stream>>>(ei2, deg2, batch2, cnt2, E, N);
  // prefix sums + dinv
  k_scan<<<1, SCAN_T, 0, stream>>>(deg1, off1, cur1, dinv1, N);
  k_scan<<<1, SCAN_T, 0, stream>>>(deg2, off2, cur2, dinv2, N);
  // CSR fill
  k_fill<<<gE, T, 0, stream>>>(ei1, cur1, dinv1, adjsrc1, adjw1, E, N);
  k_fill<<<gE, T, 0, stream>>>(ei2, cur2, dinv2, adjsrc2, adjw2, E, N);
  // branch 1: gemm -> aggregate+pool
  int gGemm = ((N + BM - 1) / BM) * (FDIM / BN);
  k_gemm<<<gGemm, 256, 0, stream>>>(x1, conv1_W, h, N);
  k_agg_pool<<<N, 256, 0, stream>>>(h, off1, adjsrc1, adjw1, conv1_b, batch1, cnt1, pool1);
  // branch 2 (reuses h; stream-ordered)
  k_gemm<<<gGemm, 256, 0, stream>>>(x2, conv2_W, h, N);
  k_agg_pool<<<N, 256, 0, stream>>>(h, off2, adjsrc2, adjw2, conv2_b, batch2, cnt2, pool2);
  // fc heads
  k_fc<<<NGRAPH, DDIM, 0, stream>>>(pool1, fc1_W, fc1_b, fco1);
  k_fc<<<NGRAPH, DDIM, 0, stream>>>(pool2, fc2_W, fc2_b, fco2);
  // final
  k_final<<<NGRAPH, DDIM, 0, stream>>>(fco1, fco2, final_W, final_b, out);
}

// Round 2
// 562.239 us; speedup vs baseline: 2.2023x; 2.2023x over previous
//
#include <hip/hip_runtime.h>
#include <cstdint>
#include <cstddef>

#define FDIM 1024   // feature dim F
#define DDIM 128    // fc out dim D
#define NGRAPH 64   // num graphs B

#define AS1 __attribute__((address_space(1)))
#define AS3 __attribute__((address_space(3)))

typedef float f32x4 __attribute__((ext_vector_type(4)));
typedef short s16x8 __attribute__((ext_vector_type(8)));

__device__ __forceinline__ unsigned short f2bf(float f) {
  unsigned int x = __float_as_uint(f);
  unsigned int r = (x + 0x7fffu + ((x >> 16) & 1u)) >> 16;  // RNE
  return (unsigned short)r;
}
__device__ __forceinline__ float bf2f(unsigned short u) {
  return __uint_as_float(((unsigned int)u) << 16);
}

// ---------------------------------------------------------------------------
// init: deg=1 (self-loop), cnt=0, pool=0
// ---------------------------------------------------------------------------
__global__ void k_init(int* deg1, int* deg2, int* cnt1, int* cnt2,
                       float* pool1, float* pool2, int N) {
  int i = blockIdx.x * blockDim.x + threadIdx.x;
  if (i < N) { deg1[i] = 1; deg2[i] = 1; }
  if (i < NGRAPH) { cnt1[i] = 0; cnt2[i] = 0; }
  if (i < NGRAPH * FDIM) { pool1[i] = 0.f; pool2[i] = 0.f; }
}

// ---------------------------------------------------------------------------
// prep: in-degree count (dst row) + nodes-per-graph count
// ---------------------------------------------------------------------------
__global__ void k_prep(const int* __restrict__ ei, int* deg,
                       const int* __restrict__ batch, int* cnt, int E, int N) {
  int i = blockIdx.x * blockDim.x + threadIdx.x;
  if (i < E) atomicAdd(&deg[ei[E + i]], 1);
  if (i < N) atomicAdd(&cnt[batch[i]], 1);
}

// ---------------------------------------------------------------------------
// scan: single-block exclusive prefix sum of deg -> off, cur; dinv = rsqrt(deg)
// ---------------------------------------------------------------------------
#define SCAN_T 1024
#define SCAN_PER 16
__global__ __launch_bounds__(SCAN_T) void k_scan(const int* __restrict__ deg,
                                                 int* off, int* cur, float* dinv, int n) {
  __shared__ int sums[SCAN_T];
  int t = threadIdx.x;
  int base = t * SCAN_PER;
  int local[SCAN_PER];
  int s = 0;
  #pragma unroll
  for (int i = 0; i < SCAN_PER; ++i) {
    int idx = base + i;
    int d = (idx < n) ? deg[idx] : 0;
    local[i] = s;
    s += d;
    if (idx < n) dinv[idx] = rsqrtf((float)d);
  }
  sums[t] = s;
  __syncthreads();
  for (int o = 1; o < SCAN_T; o <<= 1) {
    int v = (t >= o) ? sums[t - o] : 0;
    __syncthreads();
    sums[t] += v;
    __syncthreads();
  }
  int basesum = (t > 0) ? sums[t - 1] : 0;
  #pragma unroll
  for (int i = 0; i < SCAN_PER; ++i) {
    int idx = base + i;
    if (idx < n) { int o = basesum + local[i]; off[idx] = o; cur[idx] = o; }
  }
  if (t == SCAN_T - 1) off[n] = sums[SCAN_T - 1];
}

// ---------------------------------------------------------------------------
// fill: scatter edges + self-loops into CSR
// ---------------------------------------------------------------------------
__global__ void k_fill(const int* __restrict__ ei, int* cur,
                       const float* __restrict__ dinv,
                       int* adjsrc, float* adjw, int E, int N) {
  int i = blockIdx.x * blockDim.x + threadIdx.x;
  if (i < E) {
    int s = ei[i];
    int d = ei[E + i];
    int p = atomicAdd(&cur[d], 1);
    adjsrc[p] = s;
    adjw[p] = dinv[s] * dinv[d];
  }
  if (i < N) {
    int p = atomicAdd(&cur[i], 1);
    adjsrc[p] = i;
    adjw[p] = dinv[i] * dinv[i];
  }
}

// ---------------------------------------------------------------------------
// cast x (fp32) -> bf16
// ---------------------------------------------------------------------------
__global__ void k_cast_x(const float4* __restrict__ x, ushort4* __restrict__ xb, int n4) {
  int i = blockIdx.x * blockDim.x + threadIdx.x;
  if (i < n4) {
    float4 v = x[i];
    ushort4 o;
    o.x = f2bf(v.x); o.y = f2bf(v.y); o.z = f2bf(v.z); o.w = f2bf(v.w);
    xb[i] = o;
  }
}

// ---------------------------------------------------------------------------
// cast + transpose W[k][n] fp32 -> Wt[n][k] bf16  (64x64 LDS tiles)
// ---------------------------------------------------------------------------
__global__ __launch_bounds__(256) void k_cast_wt(const float* __restrict__ W,
                                                 unsigned short* __restrict__ Wt) {
  __shared__ unsigned short tile[64][65];
  int kb = blockIdx.x, nb = blockIdx.y;
  int t = threadIdx.x;
  int tn = t & 63;
  int tg = t >> 6;
  #pragma unroll
  for (int r = 0; r < 16; ++r) {
    int kk = tg * 16 + r;
    float v = W[(size_t)(kb * 64 + kk) * FDIM + nb * 64 + tn];
    tile[kk][tn] = f2bf(v);
  }
  __syncthreads();
  #pragma unroll
  for (int r = 0; r < 16; ++r) {
    int nn = tg * 16 + r;
    Wt[(size_t)(nb * 64 + nn) * FDIM + kb * 64 + tn] = tile[tn][nn];
  }
}

// ---------------------------------------------------------------------------
// GEMM bf16 MFMA (m97 structure): C[M,1024] = A[M,1024] @ Bt[1024,1024]^T
// A k-major bf16, Bt n-major-rows (Wt[n][k]) bf16, C bf16.
// 128x128 tile, BK=32, 4 waves (2x2 of 64x64), global_load_lds width 16.
// ---------------------------------------------------------------------------
__global__ __launch_bounds__(256) void k_gemm_bf16(const unsigned short* __restrict__ A,
                                                   const unsigned short* __restrict__ Bt,
                                                   unsigned short* __restrict__ C,
                                                   int M) {
  const int K = FDIM;
  __shared__ unsigned short sm[8192];  // As [0,4096) 128x32 ; Bs [4096,8192) 128x32
  int tid = threadIdx.x;
  int w = tid >> 6, lane = tid & 63;
  int wm = w >> 1, wn = w & 1;
  const int nb = FDIM / 128;  // 8
  int m0 = (blockIdx.x / nb) * 128;
  int n0 = (blockIdx.x % nb) * 128;

  int sub = lane >> 2;   // 0..15: row within 16-row staging chunk
  int kq = lane & 3;     // k quarter (8 bf16 each)

  f32x4 acc[4][4];
  #pragma unroll
  for (int i = 0; i < 4; ++i)
    #pragma unroll
    for (int j = 0; j < 4; ++j)
      acc[i][j] = (f32x4){0.f, 0.f, 0.f, 0.f};

  for (int k0 = 0; k0 < K; k0 += 32) {
    #pragma unroll
    for (int j = 0; j < 2; ++j) {
      int chunk = w * 2 + j;  // 0..7
      int ra = m0 + chunk * 16 + sub;
      if (ra > M - 1) ra = M - 1;
      const unsigned short* ga = A + (size_t)ra * K + k0 + kq * 8;
      __builtin_amdgcn_global_load_lds((const AS1 unsigned int*)ga,
                                       (AS3 unsigned int*)&sm[chunk * 512], 16, 0, 0);
      int rb = n0 + chunk * 16 + sub;
      const unsigned short* gb = Bt + (size_t)rb * K + k0 + kq * 8;
      __builtin_amdgcn_global_load_lds((const AS1 unsigned int*)gb,
                                       (AS3 unsigned int*)&sm[4096 + chunk * 512], 16, 0, 0);
    }
    __syncthreads();
    s16x8 af[4], bfr[4];
    #pragma unroll
    for (int i = 0; i < 4; ++i) {
      int rowa = wm * 64 + i * 16 + (lane & 15);
      af[i] = *(const s16x8*)&sm[rowa * 32 + (lane >> 4) * 8];
      int rowb = wn * 64 + i * 16 + (lane & 15);
      bfr[i] = *(const s16x8*)&sm[4096 + rowb * 32 + (lane >> 4) * 8];
    }
    #pragma unroll
    for (int i = 0; i < 4; ++i)
      #pragma unroll
      for (int j = 0; j < 4; ++j)
        acc[i][j] = __builtin_amdgcn_mfma_f32_16x16x32_bf16(af[i], bfr[j], acc[i][j], 0, 0, 0);
    __syncthreads();
  }

  #pragma unroll
  for (int i = 0; i < 4; ++i) {
    int row_base = m0 + wm * 64 + i * 16 + (lane >> 4) * 4;
    #pragma unroll
    for (int j = 0; j < 4; ++j) {
      int col = n0 + wn * 64 + j * 16 + (lane & 15);
      #pragma unroll
      for (int r = 0; r < 4; ++r) {
        int row = row_base + r;
        if (row < M) C[(size_t)row * FDIM + col] = f2bf(acc[i][j][r]);
      }
    }
  }
}

// ---------------------------------------------------------------------------
// aggregate (CSR gather) + bias + LeakyReLU + premultiply 1/cnt -> h2 (bf16)
// one block per dst node; no atomics.
// ---------------------------------------------------------------------------
__global__ __launch_bounds__(256) void k_agg(const unsigned short* __restrict__ h,
                                             const int* __restrict__ off,
                                             const int* __restrict__ adjsrc,
                                             const float* __restrict__ adjw,
                                             const float* __restrict__ bias,
                                             const int* __restrict__ batch,
                                             const int* __restrict__ cnt,
                                             unsigned short* __restrict__ h2) {
  int v = blockIdx.x;
  int t = threadIdx.x;  // 4 cols each
  int pb = off[v], pe = off[v + 1];
  float a0 = 0.f, a1 = 0.f, a2 = 0.f, a3 = 0.f;
  for (int p = pb; p < pe; ++p) {
    int s = adjsrc[p];
    float w = adjw[p];
    ushort4 hv = ((const ushort4*)(h + (size_t)s * FDIM))[t];
    a0 += w * bf2f(hv.x); a1 += w * bf2f(hv.y);
    a2 += w * bf2f(hv.z); a3 += w * bf2f(hv.w);
  }
  float4 b4 = ((const float4*)bias)[t];
  int g = batch[v];
  float ic = 1.0f / fmaxf((float)cnt[g], 1.0f);
  a0 += b4.x; a1 += b4.y; a2 += b4.z; a3 += b4.w;
  a0 = ((a0 >= 0.f) ? a0 : 0.01f * a0) * ic;
  a1 = ((a1 >= 0.f) ? a1 : 0.01f * a1) * ic;
  a2 = ((a2 >= 0.f) ? a2 : 0.01f * a2) * ic;
  a3 = ((a3 >= 0.f) ? a3 : 0.01f * a3) * ic;
  ushort4 o;
  o.x = f2bf(a0); o.y = f2bf(a1); o.z = f2bf(a2); o.w = f2bf(a3);
  ((ushort4*)(h2 + (size_t)v * FDIM))[t] = o;
}

// ---------------------------------------------------------------------------
// pool: sum h2 rows per graph (batch sorted -> contiguous range); grid (64,4)
// ---------------------------------------------------------------------------
__global__ __launch_bounds__(256) void k_pool(const unsigned short* __restrict__ h2,
                                              const int* __restrict__ cnt,
                                              float* pool) {
  int g = blockIdx.x, q = blockIdx.y;
  int t = threadIdx.x;
  int start = 0;
  for (int i = 0; i < g; ++i) start += cnt[i];
  int end = start + cnt[g];
  float a0 = 0.f, a1 = 0.f, a2 = 0.f, a3 = 0.f;
  for (int r = start + q; r < end; r += 4) {
    ushort4 hv = ((const ushort4*)(h2 + (size_t)r * FDIM))[t];
    a0 += bf2f(hv.x); a1 += bf2f(hv.y); a2 += bf2f(hv.z); a3 += bf2f(hv.w);
  }
  float* pg = pool + (size_t)g * FDIM + t * 4;
  atomicAdd(pg + 0, a0);
  atomicAdd(pg + 1, a1);
  atomicAdd(pg + 2, a2);
  atomicAdd(pg + 3, a3);
}

// ---------------------------------------------------------------------------
// fc: out[64,128] = leaky(pool[64,1024] @ W[1024,128] + b)
// ---------------------------------------------------------------------------
__global__ __launch_bounds__(DDIM) void k_fc(const float* __restrict__ pool,
                                             const float* __restrict__ W,
                                             const float* __restrict__ b,
                                             float* __restrict__ out) {
  int g = blockIdx.x;
  int j = threadIdx.x;
  __shared__ float xs[FDIM];
  for (int k = j; k < FDIM; k += DDIM) xs[k] = pool[(size_t)g * FDIM + k];
  __syncthreads();
  float acc = b[j];
  for (int k = 0; k < FDIM; ++k) acc += xs[k] * W[(size_t)k * DDIM + j];
  out[g * DDIM + j] = (acc >= 0.f) ? acc : 0.01f * acc;
}

// ---------------------------------------------------------------------------
// final: out[g] = concat(o1,o2) @ finalW + finalb
// ---------------------------------------------------------------------------
__global__ __launch_bounds__(DDIM) void k_final(const float* __restrict__ o1,
                                                const float* __restrict__ o2,
                                                const float* __restrict__ W,
                                                const float* __restrict__ b,
                                                float* __restrict__ out) {
  int g = blockIdx.x;
  int t = threadIdx.x;
  float acc = o1[g * DDIM + t] * W[t] + o2[g * DDIM + t] * W[DDIM + t];
  #pragma unroll
  for (int o = 32; o > 0; o >>= 1) acc += __shfl_down(acc, o);
  __shared__ float ws2[2];
  if ((t & 63) == 0) ws2[t >> 6] = acc;
  __syncthreads();
  if (t == 0) out[g] = ws2[0] + ws2[1] + b[0];
}

// ---------------------------------------------------------------------------
extern "C" void kernel_launch(void* const* d_in, const int* in_sizes, int n_in,
                              void* d_out, int out_size, void* d_ws, size_t ws_size,
                              hipStream_t stream) {
  const float* x1 = (const float*)d_in[0];
  const int* ei1 = (const int*)d_in[1];
  const int* batch1 = (const int*)d_in[2];
  const float* x2 = (const float*)d_in[3];
  const int* ei2 = (const int*)d_in[4];
  const int* batch2 = (const int*)d_in[5];
  const float* conv1_W = (const float*)d_in[10];
  const float* conv1_b = (const float*)d_in[11];
  const float* fc1_W = (const float*)d_in[12];
  const float* fc1_b = (const float*)d_in[13];
  const float* conv2_W = (const float*)d_in[14];
  const float* conv2_b = (const float*)d_in[15];
  const float* fc2_W = (const float*)d_in[16];
  const float* fc2_b = (const float*)d_in[17];
  const float* final_W = (const float*)d_in[18];
  const float* final_b = (const float*)d_in[19];
  float* out = (float*)d_out;

  const int N = in_sizes[2];      // 10000
  const int E = in_sizes[1] / 2;  // 80000
  const int A = E + N;

  size_t off_b = 0;
  auto alloc = [&](size_t bytes) -> void* {
    void* p = (char*)d_ws + off_b;
    off_b += (bytes + 255) & ~(size_t)255;
    return p;
  };
  unsigned short* hbf = (unsigned short*)alloc((size_t)N * FDIM * 2);  // gemm out (bf16)
  unsigned short* xbf = (unsigned short*)alloc((size_t)N * FDIM * 2);  // x cast; then h2
  unsigned short* h2 = xbf;  // alias: xbf dead after gemm consumes it
  unsigned short* Wt = (unsigned short*)alloc((size_t)FDIM * FDIM * 2);  // reused per branch
  int* deg1 = (int*)alloc(N * 4);
  int* deg2 = (int*)alloc(N * 4);
  int* cnt1 = (int*)alloc(NGRAPH * 4);
  int* cnt2 = (int*)alloc(NGRAPH * 4);
  int* off1 = (int*)alloc((N + 1) * 4);
  int* off2 = (int*)alloc((N + 1) * 4);
  int* cur1 = (int*)alloc(N * 4);
  int* cur2 = (int*)alloc(N * 4);
  float* dinv1 = (float*)alloc(N * 4);
  float* dinv2 = (float*)alloc(N * 4);
  int* adjsrc1 = (int*)alloc((size_t)A * 4);
  int* adjsrc2 = (int*)alloc((size_t)A * 4);
  float* adjw1 = (float*)alloc((size_t)A * 4);
  float* adjw2 = (float*)alloc((size_t)A * 4);
  float* pool1 = (float*)alloc(NGRAPH * FDIM * 4);
  float* pool2 = (float*)alloc(NGRAPH * FDIM * 4);
  float* fco1 = (float*)alloc(NGRAPH * DDIM * 4);
  float* fco2 = (float*)alloc(NGRAPH * DDIM * 4);

  const int T = 256;
  int gE = (E + T - 1) / T;
  int n4 = N * FDIM / 4;
  int gC = (n4 + T - 1) / T;
  int gGemm = ((N + 127) / 128) * (FDIM / 128);
  dim3 gWt(FDIM / 64, FDIM / 64);
  dim3 gPool(NGRAPH, 4);

  // graph prep (both branches)
  k_init<<<(NGRAPH * FDIM + T - 1) / T, T, 0, stream>>>(deg1, deg2, cnt1, cnt2, pool1, pool2, N);
  k_prep<<<gE, T, 0, stream>>>(ei1, deg1, batch1, cnt1, E, N);
  k_prep<<<gE, T, 0, stream>>>(ei2, deg2, batch2, cnt2, E, N);
  k_scan<<<1, SCAN_T, 0, stream>>>(deg1, off1, cur1, dinv1, N);
  k_scan<<<1, SCAN_T, 0, stream>>>(deg2, off2, cur2, dinv2, N);
  k_fill<<<gE, T, 0, stream>>>(ei1, cur1, dinv1, adjsrc1, adjw1, E, N);
  k_fill<<<gE, T, 0, stream>>>(ei2, cur2, dinv2, adjsrc2, adjw2, E, N);

  // branch 1
  k_cast_x<<<gC, T, 0, stream>>>((const float4*)x1, (ushort4*)xbf, n4);
  k_cast_wt<<<gWt, 256, 0, stream>>>(conv1_W, Wt);
  k_gemm_bf16<<<gGemm, 256, 0, stream>>>(xbf, Wt, hbf, N);
  k_agg<<<N, 256, 0, stream>>>(hbf, off1, adjsrc1, adjw1, conv1_b, batch1, cnt1, h2);
  k_pool<<<gPool, 256, 0, stream>>>(h2, cnt1, pool1);

  // branch 2 (reuses xbf/hbf/Wt; stream-ordered)
  k_cast_x<<<gC, T, 0, stream>>>((const float4*)x2, (ushort4*)xbf, n4);
  k_cast_wt<<<gWt, 256, 0, stream>>>(conv2_W, Wt);
  k_gemm_bf16<<<gGemm, 256, 0, stream>>>(xbf, Wt, hbf, N);
  k_agg<<<N, 256, 0, stream>>>(hbf, off2, adjsrc2, adjw2, conv2_b, batch2, cnt2, h2);
  k_pool<<<gPool, 256, 0, stream>>>(h2, cnt2, pool2);

  // heads
  k_fc<<<NGRAPH, DDIM, 0, stream>>>(pool1, fc1_W, fc1_b, fco1);
  k_fc<<<NGRAPH, DDIM, 0, stream>>>(pool2, fc2_W, fc2_b, fco2);
  k_final<<<NGRAPH, DDIM, 0, stream>>>(fco1, fco2, final_W, final_b, out);
}

// Round 3
// 443.395 us; speedup vs baseline: 2.7926x; 1.2680x over previous
//
#include <hip/hip_runtime.h>
#include <cstdint>
#include <cstddef>

#define FDIM 1024   // feature dim F
#define DDIM 128    // fc out dim D
#define NGRAPH 64   // num graphs B

#define AS1 __attribute__((address_space(1)))
#define AS3 __attribute__((address_space(3)))

typedef float f32x4 __attribute__((ext_vector_type(4)));
typedef short s16x8 __attribute__((ext_vector_type(8)));

__device__ __forceinline__ unsigned short f2bf(float f) {
  unsigned int x = __float_as_uint(f);
  unsigned int r = (x + 0x7fffu + ((x >> 16) & 1u)) >> 16;  // RNE
  return (unsigned short)r;
}
__device__ __forceinline__ float bf2f(unsigned short u) {
  return __uint_as_float(((unsigned int)u) << 16);
}

// ---------------------------------------------------------------------------
// init: deg=1 (self-loop), pool=0
// ---------------------------------------------------------------------------
__global__ void k_init(int* deg1, int* deg2, float* pool1, float* pool2, int N) {
  int i = blockIdx.x * blockDim.x + threadIdx.x;
  if (i < N) { deg1[i] = 1; deg2[i] = 1; }
  if (i < NGRAPH * FDIM) { pool1[i] = 0.f; pool2[i] = 0.f; }
}

// ---------------------------------------------------------------------------
// prep (merged branches): in-degree count only. blockIdx.y = branch.
// ---------------------------------------------------------------------------
__global__ void k_prep(const int* __restrict__ ei1, const int* __restrict__ ei2,
                       int* deg1, int* deg2, int E) {
  const int* ei = blockIdx.y ? ei2 : ei1;
  int* deg = blockIdx.y ? deg2 : deg1;
  int i = blockIdx.x * blockDim.x + threadIdx.x;
  if (i < E) atomicAdd(&deg[ei[E + i]], 1);
}

// ---------------------------------------------------------------------------
// cnt via binary search on sorted batch: cnt[g], gstart[g]. 1 block x 128.
// ---------------------------------------------------------------------------
__device__ __forceinline__ int lower_bound(const int* a, int n, int v) {
  int lo = 0, hi = n;
  while (lo < hi) {
    int mid = (lo + hi) >> 1;
    if (a[mid] < v) lo = mid + 1; else hi = mid;
  }
  return lo;
}
__global__ __launch_bounds__(128) void k_cnt(const int* __restrict__ batch1,
                                             const int* __restrict__ batch2,
                                             int* cnt1, int* gstart1,
                                             int* cnt2, int* gstart2, int N) {
  int t = threadIdx.x;
  const int* batch = (t < NGRAPH) ? batch1 : batch2;
  int* cnt = (t < NGRAPH) ? cnt1 : cnt2;
  int* gstart = (t < NGRAPH) ? gstart1 : gstart2;
  int g = t & (NGRAPH - 1);
  int lo = lower_bound(batch, N, g);
  int hi = lower_bound(batch, N, g + 1);
  gstart[g] = lo;
  cnt[g] = hi - lo;
}

// ---------------------------------------------------------------------------
// scan (merged): blockIdx.x = branch. exclusive prefix of deg -> off, cur; dinv
// ---------------------------------------------------------------------------
#define SCAN_T 1024
#define SCAN_PER 16
__global__ __launch_bounds__(SCAN_T) void k_scan(const int* __restrict__ deg1,
                                                 const int* __restrict__ deg2,
                                                 int* off1, int* off2,
                                                 int* cur1, int* cur2,
                                                 float* dinv1, float* dinv2, int n) {
  const int* deg = blockIdx.x ? deg2 : deg1;
  int* off = blockIdx.x ? off2 : off1;
  int* cur = blockIdx.x ? cur2 : cur1;
  float* dinv = blockIdx.x ? dinv2 : dinv1;
  __shared__ int sums[SCAN_T];
  int t = threadIdx.x;
  int base = t * SCAN_PER;
  int local[SCAN_PER];
  int s = 0;
  #pragma unroll
  for (int i = 0; i < SCAN_PER; ++i) {
    int idx = base + i;
    int d = (idx < n) ? deg[idx] : 0;
    local[i] = s;
    s += d;
    if (idx < n) dinv[idx] = rsqrtf((float)d);
  }
  sums[t] = s;
  __syncthreads();
  for (int o = 1; o < SCAN_T; o <<= 1) {
    int v = (t >= o) ? sums[t - o] : 0;
    __syncthreads();
    sums[t] += v;
    __syncthreads();
  }
  int basesum = (t > 0) ? sums[t - 1] : 0;
  #pragma unroll
  for (int i = 0; i < SCAN_PER; ++i) {
    int idx = base + i;
    if (idx < n) { int o = basesum + local[i]; off[idx] = o; cur[idx] = o; }
  }
  if (t == SCAN_T - 1) off[n] = sums[SCAN_T - 1];
}

// ---------------------------------------------------------------------------
// fill (merged): scatter edges + self-loops into CSR. blockIdx.y = branch.
// ---------------------------------------------------------------------------
__global__ void k_fill(const int* __restrict__ ei1, const int* __restrict__ ei2,
                       int* cur1, int* cur2,
                       const float* __restrict__ dinv1, const float* __restrict__ dinv2,
                       int* adjsrc1, int* adjsrc2,
                       float* adjw1, float* adjw2, int E, int N) {
  const int* ei = blockIdx.y ? ei2 : ei1;
  int* cur = blockIdx.y ? cur2 : cur1;
  const float* dinv = blockIdx.y ? dinv2 : dinv1;
  int* adjsrc = blockIdx.y ? adjsrc2 : adjsrc1;
  float* adjw = blockIdx.y ? adjw2 : adjw1;
  int i = blockIdx.x * blockDim.x + threadIdx.x;
  if (i < E) {
    int s = ei[i];
    int d = ei[E + i];
    int p = atomicAdd(&cur[d], 1);
    adjsrc[p] = s;
    adjw[p] = dinv[s] * dinv[d];
  }
  if (i < N) {
    int p = atomicAdd(&cur[i], 1);
    adjsrc[p] = i;
    adjw[p] = dinv[i] * dinv[i];
  }
}

// ---------------------------------------------------------------------------
// cast x (fp32) -> bf16
// ---------------------------------------------------------------------------
__global__ void k_cast_x(const float4* __restrict__ x, ushort4* __restrict__ xb, int n4) {
  int i = blockIdx.x * blockDim.x + threadIdx.x;
  if (i < n4) {
    float4 v = x[i];
    ushort4 o;
    o.x = f2bf(v.x); o.y = f2bf(v.y); o.z = f2bf(v.z); o.w = f2bf(v.w);
    xb[i] = o;
  }
}

// ---------------------------------------------------------------------------
// cast + transpose W[k][n] fp32 -> Wt[n][k] bf16  (64x64 LDS tiles)
// ---------------------------------------------------------------------------
__global__ __launch_bounds__(256) void k_cast_wt(const float* __restrict__ W,
                                                 unsigned short* __restrict__ Wt) {
  __shared__ unsigned short tile[64][65];
  int kb = blockIdx.x, nb = blockIdx.y;
  int t = threadIdx.x;
  int tn = t & 63;
  int tg = t >> 6;
  #pragma unroll
  for (int r = 0; r < 16; ++r) {
    int kk = tg * 16 + r;
    float v = W[(size_t)(kb * 64 + kk) * FDIM + nb * 64 + tn];
    tile[kk][tn] = f2bf(v);
  }
  __syncthreads();
  #pragma unroll
  for (int r = 0; r < 16; ++r) {
    int nn = tg * 16 + r;
    Wt[(size_t)(nb * 64 + nn) * FDIM + kb * 64 + tn] = tile[tn][nn];
  }
}

// ---------------------------------------------------------------------------
// GEMM bf16 MFMA: C[M,1024] = A[M,1024] @ Bt[1024,1024]^T
// 128x128 tile, BK=32, 4 waves (2x2 of 64x64), global_load_lds width 16.
// ---------------------------------------------------------------------------
__global__ __launch_bounds__(256) void k_gemm_bf16(const unsigned short* __restrict__ A,
                                                   const unsigned short* __restrict__ Bt,
                                                   unsigned short* __restrict__ C,
                                                   int M) {
  const int K = FDIM;
  __shared__ unsigned short sm[8192];  // As [0,4096) 128x32 ; Bs [4096,8192) 128x32
  int tid = threadIdx.x;
  int w = tid >> 6, lane = tid & 63;
  int wm = w >> 1, wn = w & 1;
  const int nb = FDIM / 128;  // 8
  int m0 = (blockIdx.x / nb) * 128;
  int n0 = (blockIdx.x % nb) * 128;

  int sub = lane >> 2;
  int kq = lane & 3;

  f32x4 acc[4][4];
  #pragma unroll
  for (int i = 0; i < 4; ++i)
    #pragma unroll
    for (int j = 0; j < 4; ++j)
      acc[i][j] = (f32x4){0.f, 0.f, 0.f, 0.f};

  for (int k0 = 0; k0 < K; k0 += 32) {
    #pragma unroll
    for (int j = 0; j < 2; ++j) {
      int chunk = w * 2 + j;
      int ra = m0 + chunk * 16 + sub;
      if (ra > M - 1) ra = M - 1;
      const unsigned short* ga = A + (size_t)ra * K + k0 + kq * 8;
      __builtin_amdgcn_global_load_lds((const AS1 unsigned int*)ga,
                                       (AS3 unsigned int*)&sm[chunk * 512], 16, 0, 0);
      int rb = n0 + chunk * 16 + sub;
      const unsigned short* gb = Bt + (size_t)rb * K + k0 + kq * 8;
      __builtin_amdgcn_global_load_lds((const AS1 unsigned int*)gb,
                                       (AS3 unsigned int*)&sm[4096 + chunk * 512], 16, 0, 0);
    }
    __syncthreads();
    s16x8 af[4], bfr[4];
    #pragma unroll
    for (int i = 0; i < 4; ++i) {
      int rowa = wm * 64 + i * 16 + (lane & 15);
      af[i] = *(const s16x8*)&sm[rowa * 32 + (lane >> 4) * 8];
      int rowb = wn * 64 + i * 16 + (lane & 15);
      bfr[i] = *(const s16x8*)&sm[4096 + rowb * 32 + (lane >> 4) * 8];
    }
    #pragma unroll
    for (int i = 0; i < 4; ++i)
      #pragma unroll
      for (int j = 0; j < 4; ++j)
        acc[i][j] = __builtin_amdgcn_mfma_f32_16x16x32_bf16(af[i], bfr[j], acc[i][j], 0, 0, 0);
    __syncthreads();
  }

  #pragma unroll
  for (int i = 0; i < 4; ++i) {
    int row_base = m0 + wm * 64 + i * 16 + (lane >> 4) * 4;
    #pragma unroll
    for (int j = 0; j < 4; ++j) {
      int col = n0 + wn * 64 + j * 16 + (lane & 15);
      #pragma unroll
      for (int r = 0; r < 4; ++r) {
        int row = row_base + r;
        if (row < M) C[(size_t)row * FDIM + col] = f2bf(acc[i][j][r]);
      }
    }
  }
}

// ---------------------------------------------------------------------------
// aggregate (CSR gather) + bias + LeakyReLU + premultiply 1/cnt -> h2 (bf16)
// ---------------------------------------------------------------------------
__global__ __launch_bounds__(256) void k_agg(const unsigned short* __restrict__ h,
                                             const int* __restrict__ off,
                                             const int* __restrict__ adjsrc,
                                             const float* __restrict__ adjw,
                                             const float* __restrict__ bias,
                                             const int* __restrict__ batch,
                                             const int* __restrict__ cnt,
                                             unsigned short* __restrict__ h2) {
  int v = blockIdx.x;
  int t = threadIdx.x;
  int pb = off[v], pe = off[v + 1];
  float a0 = 0.f, a1 = 0.f, a2 = 0.f, a3 = 0.f;
  for (int p = pb; p < pe; ++p) {
    int s = adjsrc[p];
    float w = adjw[p];
    ushort4 hv = ((const ushort4*)(h + (size_t)s * FDIM))[t];
    a0 += w * bf2f(hv.x); a1 += w * bf2f(hv.y);
    a2 += w * bf2f(hv.z); a3 += w * bf2f(hv.w);
  }
  float4 b4 = ((const float4*)bias)[t];
  int g = batch[v];
  float ic = 1.0f / fmaxf((float)cnt[g], 1.0f);
  a0 += b4.x; a1 += b4.y; a2 += b4.z; a3 += b4.w;
  a0 = ((a0 >= 0.f) ? a0 : 0.01f * a0) * ic;
  a1 = ((a1 >= 0.f) ? a1 : 0.01f * a1) * ic;
  a2 = ((a2 >= 0.f) ? a2 : 0.01f * a2) * ic;
  a3 = ((a3 >= 0.f) ? a3 : 0.01f * a3) * ic;
  ushort4 o;
  o.x = f2bf(a0); o.y = f2bf(a1); o.z = f2bf(a2); o.w = f2bf(a3);
  ((ushort4*)(h2 + (size_t)v * FDIM))[t] = o;
}

// ---------------------------------------------------------------------------
// pool: sum h2 rows per graph using gstart/cnt; grid (64,4)
// ---------------------------------------------------------------------------
__global__ __launch_bounds__(256) void k_pool(const unsigned short* __restrict__ h2,
                                              const int* __restrict__ cnt,
                                              const int* __restrict__ gstart,
                                              float* pool) {
  int g = blockIdx.x, q = blockIdx.y;
  int t = threadIdx.x;
  int start = gstart[g];
  int end = start + cnt[g];
  float a0 = 0.f, a1 = 0.f, a2 = 0.f, a3 = 0.f;
  for (int r = start + q; r < end; r += 4) {
    ushort4 hv = ((const ushort4*)(h2 + (size_t)r * FDIM))[t];
    a0 += bf2f(hv.x); a1 += bf2f(hv.y); a2 += bf2f(hv.z); a3 += bf2f(hv.w);
  }
  float* pg = pool + (size_t)g * FDIM + t * 4;
  atomicAdd(pg + 0, a0);
  atomicAdd(pg + 1, a1);
  atomicAdd(pg + 2, a2);
  atomicAdd(pg + 3, a3);
}

// ---------------------------------------------------------------------------
// fc: out[64,128] = leaky(pool[64,1024] @ W[1024,128] + b)
// ---------------------------------------------------------------------------
__global__ __launch_bounds__(DDIM) void k_fc(const float* __restrict__ pool,
                                             const float* __restrict__ W,
                                             const float* __restrict__ b,
                                             float* __restrict__ out) {
  int g = blockIdx.x;
  int j = threadIdx.x;
  __shared__ float xs[FDIM];
  for (int k = j; k < FDIM; k += DDIM) xs[k] = pool[(size_t)g * FDIM + k];
  __syncthreads();
  float acc = b[j];
  for (int k = 0; k < FDIM; ++k) acc += xs[k] * W[(size_t)k * DDIM + j];
  out[g * DDIM + j] = (acc >= 0.f) ? acc : 0.01f * acc;
}

// ---------------------------------------------------------------------------
// final: out[g] = concat(o1,o2) @ finalW + finalb
// ---------------------------------------------------------------------------
__global__ __launch_bounds__(DDIM) void k_final(const float* __restrict__ o1,
                                                const float* __restrict__ o2,
                                                const float* __restrict__ W,
                                                const float* __restrict__ b,
                                                float* __restrict__ out) {
  int g = blockIdx.x;
  int t = threadIdx.x;
  float acc = o1[g * DDIM + t] * W[t] + o2[g * DDIM + t] * W[DDIM + t];
  #pragma unroll
  for (int o = 32; o > 0; o >>= 1) acc += __shfl_down(acc, o);
  __shared__ float ws2[2];
  if ((t & 63) == 0) ws2[t >> 6] = acc;
  __syncthreads();
  if (t == 0) out[g] = ws2[0] + ws2[1] + b[0];
}

// ---------------------------------------------------------------------------
extern "C" void kernel_launch(void* const* d_in, const int* in_sizes, int n_in,
                              void* d_out, int out_size, void* d_ws, size_t ws_size,
                              hipStream_t stream) {
  const float* x1 = (const float*)d_in[0];
  const int* ei1 = (const int*)d_in[1];
  const int* batch1 = (const int*)d_in[2];
  const float* x2 = (const float*)d_in[3];
  const int* ei2 = (const int*)d_in[4];
  const int* batch2 = (const int*)d_in[5];
  const float* conv1_W = (const float*)d_in[10];
  const float* conv1_b = (const float*)d_in[11];
  const float* fc1_W = (const float*)d_in[12];
  const float* fc1_b = (const float*)d_in[13];
  const float* conv2_W = (const float*)d_in[14];
  const float* conv2_b = (const float*)d_in[15];
  const float* fc2_W = (const float*)d_in[16];
  const float* fc2_b = (const float*)d_in[17];
  const float* final_W = (const float*)d_in[18];
  const float* final_b = (const float*)d_in[19];
  float* out = (float*)d_out;

  const int N = in_sizes[2];      // 10000
  const int E = in_sizes[1] / 2;  // 80000
  const int A = E + N;

  size_t off_b = 0;
  auto alloc = [&](size_t bytes) -> void* {
    void* p = (char*)d_ws + off_b;
    off_b += (bytes + 255) & ~(size_t)255;
    return p;
  };
  unsigned short* hbf = (unsigned short*)alloc((size_t)N * FDIM * 2);
  unsigned short* xbf = (unsigned short*)alloc((size_t)N * FDIM * 2);
  unsigned short* h2 = xbf;  // alias: xbf dead after gemm consumes it
  unsigned short* Wt = (unsigned short*)alloc((size_t)FDIM * FDIM * 2);
  int* deg1 = (int*)alloc(N * 4);
  int* deg2 = (int*)alloc(N * 4);
  int* cnt1 = (int*)alloc(NGRAPH * 4);
  int* cnt2 = (int*)alloc(NGRAPH * 4);
  int* gstart1 = (int*)alloc(NGRAPH * 4);
  int* gstart2 = (int*)alloc(NGRAPH * 4);
  int* off1 = (int*)alloc((N + 1) * 4);
  int* off2 = (int*)alloc((N + 1) * 4);
  int* cur1 = (int*)alloc(N * 4);
  int* cur2 = (int*)alloc(N * 4);
  float* dinv1 = (float*)alloc(N * 4);
  float* dinv2 = (float*)alloc(N * 4);
  int* adjsrc1 = (int*)alloc((size_t)A * 4);
  int* adjsrc2 = (int*)alloc((size_t)A * 4);
  float* adjw1 = (float*)alloc((size_t)A * 4);
  float* adjw2 = (float*)alloc((size_t)A * 4);
  float* pool1 = (float*)alloc(NGRAPH * FDIM * 4);
  float* pool2 = (float*)alloc(NGRAPH * FDIM * 4);
  float* fco1 = (float*)alloc(NGRAPH * DDIM * 4);
  float* fco2 = (float*)alloc(NGRAPH * DDIM * 4);

  const int T = 256;
  int gE = (E + T - 1) / T;
  int n4 = N * FDIM / 4;
  int gC = (n4 + T - 1) / T;
  int gGemm = ((N + 127) / 128) * (FDIM / 128);
  dim3 gWt(FDIM / 64, FDIM / 64);
  dim3 gPool(NGRAPH, 4);
  dim3 gPrep(gE, 2);
  dim3 gFill(gE, 2);

  // graph prep (both branches, merged launches)
  k_init<<<(NGRAPH * FDIM + T - 1) / T, T, 0, stream>>>(deg1, deg2, pool1, pool2, N);
  k_cnt<<<1, 128, 0, stream>>>(batch1, batch2, cnt1, gstart1, cnt2, gstart2, N);
  k_prep<<<gPrep, T, 0, stream>>>(ei1, ei2, deg1, deg2, E);
  k_scan<<<2, SCAN_T, 0, stream>>>(deg1, deg2, off1, off2, cur1, cur2, dinv1, dinv2, N);
  k_fill<<<gFill, T, 0, stream>>>(ei1, ei2, cur1, cur2, dinv1, dinv2,
                                  adjsrc1, adjsrc2, adjw1, adjw2, E, N);

  // branch 1
  k_cast_x<<<gC, T, 0, stream>>>((const float4*)x1, (ushort4*)xbf, n4);
  k_cast_wt<<<gWt, 256, 0, stream>>>(conv1_W, Wt);
  k_gemm_bf16<<<gGemm, 256, 0, stream>>>(xbf, Wt, hbf, N);
  k_agg<<<N, 256, 0, stream>>>(hbf, off1, adjsrc1, adjw1, conv1_b, batch1, cnt1, h2);
  k_pool<<<gPool, 256, 0, stream>>>(h2, cnt1, gstart1, pool1);

  // branch 2 (reuses xbf/hbf/Wt; stream-ordered)
  k_cast_x<<<gC, T, 0, stream>>>((const float4*)x2, (ushort4*)xbf, n4);
  k_cast_wt<<<gWt, 256, 0, stream>>>(conv2_W, Wt);
  k_gemm_bf16<<<gGemm, 256, 0, stream>>>(xbf, Wt, hbf, N);
  k_agg<<<N, 256, 0, stream>>>(hbf, off2, adjsrc2, adjw2, conv2_b, batch2, cnt2, h2);
  k_pool<<<gPool, 256, 0, stream>>>(h2, cnt2, gstart2, pool2);

  // heads
  k_fc<<<NGRAPH, DDIM, 0, stream>>>(pool1, fc1_W, fc1_b, fco1);
  k_fc<<<NGRAPH, DDIM, 0, stream>>>(pool2, fc2_W, fc2_b, fco2);
  k_final<<<NGRAPH, DDIM, 0, stream>>>(fco1, fco2, final_W, final_b, out);
}

// Round 4
// 365.619 us; speedup vs baseline: 3.3866x; 1.2127x over previous
//
#include <hip/hip_runtime.h>
#include <cstdint>
#include <cstddef>

#define FDIM 1024   // feature dim F
#define DDIM 128    // fc out dim D
#define NGRAPH 64   // num graphs B
#define CHUNKS 16   // pool chunks per graph

#define AS1 __attribute__((address_space(1)))
#define AS3 __attribute__((address_space(3)))

typedef float f32x4 __attribute__((ext_vector_type(4)));
typedef short s16x8 __attribute__((ext_vector_type(8)));

__device__ __forceinline__ unsigned short f2bf(float f) {
  unsigned int x = __float_as_uint(f);
  unsigned int r = (x + 0x7fffu + ((x >> 16) & 1u)) >> 16;  // RNE
  return (unsigned short)r;
}
__device__ __forceinline__ float bf2f(unsigned short u) {
  return __uint_as_float(((unsigned int)u) << 16);
}

// ---------------------------------------------------------------------------
// init + cnt: blocks 0..63 pool1=0, 64..127 pool2=0, 128..167 deg1=1,
// 168..207 deg2=1, 208 = binary-search cnt/gstart for both batches.
// ---------------------------------------------------------------------------
__device__ __forceinline__ int lower_bound(const int* a, int n, int v) {
  int lo = 0, hi = n;
  while (lo < hi) {
    int mid = (lo + hi) >> 1;
    if (a[mid] < v) lo = mid + 1; else hi = mid;
  }
  return lo;
}
__global__ __launch_bounds__(256) void k_init_cnt(float4* pool1, float4* pool2,
                                                  int* deg1, int* deg2,
                                                  const int* __restrict__ batch1,
                                                  const int* __restrict__ batch2,
                                                  int* cnt1, int* gstart1,
                                                  int* cnt2, int* gstart2, int N) {
  int bid = blockIdx.x, t = threadIdx.x;
  const float4 z = make_float4(0.f, 0.f, 0.f, 0.f);
  if (bid < 64) {
    pool1[bid * 256 + t] = z;
  } else if (bid < 128) {
    pool2[(bid - 64) * 256 + t] = z;
  } else if (bid < 168) {
    int i = (bid - 128) * 256 + t;
    if (i < N) deg1[i] = 1;
  } else if (bid < 208) {
    int i = (bid - 168) * 256 + t;
    if (i < N) deg2[i] = 1;
  } else {
    if (t < 128) {
      const int* batch = (t < NGRAPH) ? batch1 : batch2;
      int* cnt = (t < NGRAPH) ? cnt1 : cnt2;
      int* gstart = (t < NGRAPH) ? gstart1 : gstart2;
      int g = t & (NGRAPH - 1);
      int lo = lower_bound(batch, N, g);
      int hi = lower_bound(batch, N, g + 1);
      gstart[g] = lo;
      cnt[g] = hi - lo;
    }
  }
}

// ---------------------------------------------------------------------------
// prep (merged branches): in-degree count. blockIdx.y = branch.
// ---------------------------------------------------------------------------
__global__ void k_prep(const int* __restrict__ ei1, const int* __restrict__ ei2,
                       int* deg1, int* deg2, int E) {
  const int* ei = blockIdx.y ? ei2 : ei1;
  int* deg = blockIdx.y ? deg2 : deg1;
  int i = blockIdx.x * blockDim.x + threadIdx.x;
  if (i < E) atomicAdd(&deg[ei[E + i]], 1);
}

// ---------------------------------------------------------------------------
// scan (merged): blockIdx.x = branch. exclusive prefix of deg -> off, cur; dinv
// ---------------------------------------------------------------------------
#define SCAN_T 1024
#define SCAN_PER 16
__global__ __launch_bounds__(SCAN_T) void k_scan(const int* __restrict__ deg1,
                                                 const int* __restrict__ deg2,
                                                 int* off1, int* off2,
                                                 int* cur1, int* cur2,
                                                 float* dinv1, float* dinv2, int n) {
  const int* deg = blockIdx.x ? deg2 : deg1;
  int* off = blockIdx.x ? off2 : off1;
  int* cur = blockIdx.x ? cur2 : cur1;
  float* dinv = blockIdx.x ? dinv2 : dinv1;
  __shared__ int sums[SCAN_T];
  int t = threadIdx.x;
  int base = t * SCAN_PER;
  int local[SCAN_PER];
  int s = 0;
  #pragma unroll
  for (int i = 0; i < SCAN_PER; ++i) {
    int idx = base + i;
    int d = (idx < n) ? deg[idx] : 0;
    local[i] = s;
    s += d;
    if (idx < n) dinv[idx] = rsqrtf((float)d);
  }
  sums[t] = s;
  __syncthreads();
  for (int o = 1; o < SCAN_T; o <<= 1) {
    int v = (t >= o) ? sums[t - o] : 0;
    __syncthreads();
    sums[t] += v;
    __syncthreads();
  }
  int basesum = (t > 0) ? sums[t - 1] : 0;
  #pragma unroll
  for (int i = 0; i < SCAN_PER; ++i) {
    int idx = base + i;
    if (idx < n) { int o = basesum + local[i]; off[idx] = o; cur[idx] = o; }
  }
  if (t == SCAN_T - 1) off[n] = sums[SCAN_T - 1];
}

// ---------------------------------------------------------------------------
// fill (merged): scatter edges + self-loops into CSR. blockIdx.y = branch.
// ---------------------------------------------------------------------------
__global__ void k_fill(const int* __restrict__ ei1, const int* __restrict__ ei2,
                       int* cur1, int* cur2,
                       const float* __restrict__ dinv1, const float* __restrict__ dinv2,
                       int* adjsrc1, int* adjsrc2,
                       float* adjw1, float* adjw2, int E, int N) {
  const int* ei = blockIdx.y ? ei2 : ei1;
  int* cur = blockIdx.y ? cur2 : cur1;
  const float* dinv = blockIdx.y ? dinv2 : dinv1;
  int* adjsrc = blockIdx.y ? adjsrc2 : adjsrc1;
  float* adjw = blockIdx.y ? adjw2 : adjw1;
  int i = blockIdx.x * blockDim.x + threadIdx.x;
  if (i < E) {
    int s = ei[i];
    int d = ei[E + i];
    int p = atomicAdd(&cur[d], 1);
    adjsrc[p] = s;
    adjw[p] = dinv[s] * dinv[d];
  }
  if (i < N) {
    int p = atomicAdd(&cur[i], 1);
    adjsrc[p] = i;
    adjw[p] = dinv[i] * dinv[i];
  }
}

// ---------------------------------------------------------------------------
// cast (merged): blocks [0, 2*nxb) cast x1/x2 fp32->bf16;
// blocks [2*nxb, 2*nxb+512) cast+transpose W1/W2 (64x64 LDS tiles).
// ---------------------------------------------------------------------------
__global__ __launch_bounds__(256) void k_cast(const float4* __restrict__ x1,
                                              const float4* __restrict__ x2,
                                              const float* __restrict__ W1,
                                              const float* __restrict__ W2,
                                              ushort4* xb1, ushort4* xb2,
                                              unsigned short* Wt1, unsigned short* Wt2,
                                              int n4, int nxb) {
  __shared__ unsigned short tile[64][65];
  int bid = blockIdx.x, t = threadIdx.x;
  if (bid < 2 * nxb) {
    int br = bid >= nxb;
    const float4* x = br ? x2 : x1;
    ushort4* xb = br ? xb2 : xb1;
    int i = (bid - br * nxb) * 256 + t;
    if (i < n4) {
      float4 v = x[i];
      ushort4 o;
      o.x = f2bf(v.x); o.y = f2bf(v.y); o.z = f2bf(v.z); o.w = f2bf(v.w);
      xb[i] = o;
    }
  } else {
    int w = bid - 2 * nxb;
    int br = w >= 256;
    const float* W = br ? W2 : W1;
    unsigned short* Wt = br ? Wt2 : Wt1;
    int tid16 = w - br * 256;
    int kb = tid16 >> 4, nb = tid16 & 15;
    int tn = t & 63, tg = t >> 6;
    #pragma unroll
    for (int r = 0; r < 16; ++r) {
      int kk = tg * 16 + r;
      tile[kk][tn] = f2bf(W[(size_t)(kb * 64 + kk) * FDIM + nb * 64 + tn]);
    }
    __syncthreads();
    #pragma unroll
    for (int r = 0; r < 16; ++r) {
      int nn = tg * 16 + r;
      Wt[(size_t)(nb * 64 + nn) * FDIM + kb * 64 + tn] = tile[tn][nn];
    }
  }
}

// ---------------------------------------------------------------------------
// GEMM bf16 MFMA: C[M,1024] = A[M,1024] @ Wt[1024,1024]^T (Wt is n-major)
// 128x128 tile, BK=32, 4 waves, global_load_lds width 16.
// blockIdx.y = branch. XCD swizzle: blocks with equal bid%8 (same XCD under
// round-robin dispatch) cover complete m-tiles -> A-tile fetched by ~1 XCD L2.
// ---------------------------------------------------------------------------
__global__ __launch_bounds__(256) void k_gemm_bf16(const unsigned short* __restrict__ A1,
                                                   const unsigned short* __restrict__ A2,
                                                   const unsigned short* __restrict__ B1,
                                                   const unsigned short* __restrict__ B2,
                                                   unsigned short* __restrict__ C1,
                                                   unsigned short* __restrict__ C2,
                                                   int M) {
  const unsigned short* A = blockIdx.y ? A2 : A1;
  const unsigned short* Bt = blockIdx.y ? B2 : B1;
  unsigned short* C = blockIdx.y ? C2 : C1;
  const int K = FDIM;
  __shared__ unsigned short sm[8192];  // As [0,4096) 128x32 ; Bs [4096,8192) 128x32
  int tid = threadIdx.x;
  int w = tid >> 6, lane = tid & 63;
  int wm = w >> 1, wn = w & 1;

  // XCD swizzle: grid.x = mt*8 (divisible by 8)
  int per_xcd = gridDim.x >> 3;                       // blocks per XCD
  int l = (blockIdx.x & 7) * per_xcd + (blockIdx.x >> 3);
  int m0 = (l >> 3) * 128;                            // nt == 8
  int n0 = (l & 7) * 128;

  int sub = lane >> 2;
  int kq = lane & 3;

  f32x4 acc[4][4];
  #pragma unroll
  for (int i = 0; i < 4; ++i)
    #pragma unroll
    for (int j = 0; j < 4; ++j)
      acc[i][j] = (f32x4){0.f, 0.f, 0.f, 0.f};

  for (int k0 = 0; k0 < K; k0 += 32) {
    #pragma unroll
    for (int j = 0; j < 2; ++j) {
      int chunk = w * 2 + j;
      int ra = m0 + chunk * 16 + sub;
      if (ra > M - 1) ra = M - 1;
      const unsigned short* ga = A + (size_t)ra * K + k0 + kq * 8;
      __builtin_amdgcn_global_load_lds((const AS1 unsigned int*)ga,
                                       (AS3 unsigned int*)&sm[chunk * 512], 16, 0, 0);
      int rb = n0 + chunk * 16 + sub;
      const unsigned short* gb = Bt + (size_t)rb * K + k0 + kq * 8;
      __builtin_amdgcn_global_load_lds((const AS1 unsigned int*)gb,
                                       (AS3 unsigned int*)&sm[4096 + chunk * 512], 16, 0, 0);
    }
    __syncthreads();
    s16x8 af[4], bfr[4];
    #pragma unroll
    for (int i = 0; i < 4; ++i) {
      int rowa = wm * 64 + i * 16 + (lane & 15);
      af[i] = *(const s16x8*)&sm[rowa * 32 + (lane >> 4) * 8];
      int rowb = wn * 64 + i * 16 + (lane & 15);
      bfr[i] = *(const s16x8*)&sm[4096 + rowb * 32 + (lane >> 4) * 8];
    }
    #pragma unroll
    for (int i = 0; i < 4; ++i)
      #pragma unroll
      for (int j = 0; j < 4; ++j)
        acc[i][j] = __builtin_amdgcn_mfma_f32_16x16x32_bf16(af[i], bfr[j], acc[i][j], 0, 0, 0);
    __syncthreads();
  }

  #pragma unroll
  for (int i = 0; i < 4; ++i) {
    int row_base = m0 + wm * 64 + i * 16 + (lane >> 4) * 4;
    #pragma unroll
    for (int j = 0; j < 4; ++j) {
      int col = n0 + wn * 64 + j * 16 + (lane & 15);
      #pragma unroll
      for (int r = 0; r < 4; ++r) {
        int row = row_base + r;
        if (row < M) C[(size_t)row * FDIM + col] = f2bf(acc[i][j][r]);
      }
    }
  }
}

// ---------------------------------------------------------------------------
// aggpool (fused): grid (64, CHUNKS, 2). Each block aggregates a node range of
// one graph (CSR gather + bias + LeakyReLU), accumulates the graph partial sum
// in registers, one atomicAdd set per block into pool (pre-scaled by 1/cnt).
// ---------------------------------------------------------------------------
__global__ __launch_bounds__(256) void k_aggpool(const unsigned short* __restrict__ h1,
                                                 const unsigned short* __restrict__ h2,
                                                 const int* __restrict__ off1,
                                                 const int* __restrict__ off2,
                                                 const int* __restrict__ adjsrc1,
                                                 const int* __restrict__ adjsrc2,
                                                 const float* __restrict__ adjw1,
                                                 const float* __restrict__ adjw2,
                                                 const float* __restrict__ bias1,
                                                 const float* __restrict__ bias2,
                                                 const int* __restrict__ cnt1,
                                                 const int* __restrict__ cnt2,
                                                 const int* __restrict__ gstart1,
                                                 const int* __restrict__ gstart2,
                                                 float* pool1, float* pool2) {
  int br = blockIdx.z;
  const unsigned short* h = br ? h2 : h1;
  const int* off = br ? off2 : off1;
  const int* adjsrc = br ? adjsrc2 : adjsrc1;
  const float* adjw = br ? adjw2 : adjw1;
  const float* bias = br ? bias2 : bias1;
  const int* cnt = br ? cnt2 : cnt1;
  const int* gstart = br ? gstart2 : gstart1;
  float* pool = br ? pool2 : pool1;

  int g = blockIdx.x, q = blockIdx.y;
  int t = threadIdx.x;
  int n = cnt[g];
  int start = gstart[g];
  int per = (n + CHUNKS - 1) / CHUNKS;
  int v0 = start + q * per;
  int v1 = min(start + n, v0 + per);
  if (v0 >= v1) return;

  float4 b4 = ((const float4*)bias)[t];
  float s0 = 0.f, s1 = 0.f, s2 = 0.f, s3 = 0.f;
  for (int v = v0; v < v1; ++v) {
    int pb = off[v], pe = off[v + 1];
    float a0 = 0.f, a1 = 0.f, a2 = 0.f, a3 = 0.f;
    for (int p = pb; p < pe; ++p) {
      int sidx = adjsrc[p];
      float wgt = adjw[p];
      ushort4 hv = ((const ushort4*)(h + (size_t)sidx * FDIM))[t];
      a0 += wgt * bf2f(hv.x); a1 += wgt * bf2f(hv.y);
      a2 += wgt * bf2f(hv.z); a3 += wgt * bf2f(hv.w);
    }
    a0 += b4.x; a1 += b4.y; a2 += b4.z; a3 += b4.w;
    s0 += (a0 >= 0.f) ? a0 : 0.01f * a0;
    s1 += (a1 >= 0.f) ? a1 : 0.01f * a1;
    s2 += (a2 >= 0.f) ? a2 : 0.01f * a2;
    s3 += (a3 >= 0.f) ? a3 : 0.01f * a3;
  }
  float ic = 1.0f / fmaxf((float)n, 1.0f);
  float* pg = pool + (size_t)g * FDIM + t * 4;
  atomicAdd(pg + 0, s0 * ic);
  atomicAdd(pg + 1, s1 * ic);
  atomicAdd(pg + 2, s2 * ic);
  atomicAdd(pg + 3, s3 * ic);
}

// ---------------------------------------------------------------------------
// fc (merged): blockIdx.y = branch. out[64,128] = leaky(pool @ W + b)
// ---------------------------------------------------------------------------
__global__ __launch_bounds__(DDIM) void k_fc(const float* __restrict__ pool1,
                                             const float* __restrict__ pool2,
                                             const float* __restrict__ W1,
                                             const float* __restrict__ W2,
                                             const float* __restrict__ b1,
                                             const float* __restrict__ b2,
                                             float* out1, float* out2) {
  const float* pool = blockIdx.y ? pool2 : pool1;
  const float* W = blockIdx.y ? W2 : W1;
  const float* b = blockIdx.y ? b2 : b1;
  float* out = blockIdx.y ? out2 : out1;
  int g = blockIdx.x;
  int j = threadIdx.x;
  __shared__ float xs[FDIM];
  for (int k = j; k < FDIM; k += DDIM) xs[k] = pool[(size_t)g * FDIM + k];
  __syncthreads();
  float acc = b[j];
  for (int k = 0; k < FDIM; ++k) acc += xs[k] * W[(size_t)k * DDIM + j];
  out[g * DDIM + j] = (acc >= 0.f) ? acc : 0.01f * acc;
}

// ---------------------------------------------------------------------------
// final: out[g] = concat(o1,o2) @ finalW + finalb
// ---------------------------------------------------------------------------
__global__ __launch_bounds__(DDIM) void k_final(const float* __restrict__ o1,
                                                const float* __restrict__ o2,
                                                const float* __restrict__ W,
                                                const float* __restrict__ b,
                                                float* __restrict__ out) {
  int g = blockIdx.x;
  int t = threadIdx.x;
  float acc = o1[g * DDIM + t] * W[t] + o2[g * DDIM + t] * W[DDIM + t];
  #pragma unroll
  for (int o = 32; o > 0; o >>= 1) acc += __shfl_down(acc, o);
  __shared__ float ws2[2];
  if ((t & 63) == 0) ws2[t >> 6] = acc;
  __syncthreads();
  if (t == 0) out[g] = ws2[0] + ws2[1] + b[0];
}

// ---------------------------------------------------------------------------
extern "C" void kernel_launch(void* const* d_in, const int* in_sizes, int n_in,
                              void* d_out, int out_size, void* d_ws, size_t ws_size,
                              hipStream_t stream) {
  const float* x1 = (const float*)d_in[0];
  const int* ei1 = (const int*)d_in[1];
  const int* batch1 = (const int*)d_in[2];
  const float* x2 = (const float*)d_in[3];
  const int* ei2 = (const int*)d_in[4];
  const int* batch2 = (const int*)d_in[5];
  const float* conv1_W = (const float*)d_in[10];
  const float* conv1_b = (const float*)d_in[11];
  const float* fc1_W = (const float*)d_in[12];
  const float* fc1_b = (const float*)d_in[13];
  const float* conv2_W = (const float*)d_in[14];
  const float* conv2_b = (const float*)d_in[15];
  const float* fc2_W = (const float*)d_in[16];
  const float* fc2_b = (const float*)d_in[17];
  const float* final_W = (const float*)d_in[18];
  const float* final_b = (const float*)d_in[19];
  float* out = (float*)d_out;

  const int N = in_sizes[2];      // 10000
  const int E = in_sizes[1] / 2;  // 80000
  const int A = E + N;

  size_t off_b = 0;
  auto alloc = [&](size_t bytes) -> void* {
    void* p = (char*)d_ws + off_b;
    off_b += (bytes + 255) & ~(size_t)255;
    return p;
  };
  unsigned short* xbf1 = (unsigned short*)alloc((size_t)N * FDIM * 2);
  unsigned short* xbf2 = (unsigned short*)alloc((size_t)N * FDIM * 2);
  unsigned short* hbf1 = (unsigned short*)alloc((size_t)N * FDIM * 2);
  unsigned short* hbf2 = (unsigned short*)alloc((size_t)N * FDIM * 2);
  unsigned short* Wt1 = (unsigned short*)alloc((size_t)FDIM * FDIM * 2);
  unsigned short* Wt2 = (unsigned short*)alloc((size_t)FDIM * FDIM * 2);
  int* deg1 = (int*)alloc(N * 4);
  int* deg2 = (int*)alloc(N * 4);
  int* cnt1 = (int*)alloc(NGRAPH * 4);
  int* cnt2 = (int*)alloc(NGRAPH * 4);
  int* gstart1 = (int*)alloc(NGRAPH * 4);
  int* gstart2 = (int*)alloc(NGRAPH * 4);
  int* off1 = (int*)alloc((N + 1) * 4);
  int* off2 = (int*)alloc((N + 1) * 4);
  int* cur1 = (int*)alloc(N * 4);
  int* cur2 = (int*)alloc(N * 4);
  float* dinv1 = (float*)alloc(N * 4);
  float* dinv2 = (float*)alloc(N * 4);
  int* adjsrc1 = (int*)alloc((size_t)A * 4);
  int* adjsrc2 = (int*)alloc((size_t)A * 4);
  float* adjw1 = (float*)alloc((size_t)A * 4);
  float* adjw2 = (float*)alloc((size_t)A * 4);
  float* pool1 = (float*)alloc(NGRAPH * FDIM * 4);
  float* pool2 = (float*)alloc(NGRAPH * FDIM * 4);
  float* fco1 = (float*)alloc(NGRAPH * DDIM * 4);
  float* fco2 = (float*)alloc(NGRAPH * DDIM * 4);

  const int T = 256;
  int gE = (E + T - 1) / T;
  int n4 = N * FDIM / 4;
  int nxb = (n4 + T - 1) / T;               // x-cast blocks per branch
  int mt = (N + 127) / 128;                 // 79 m-tiles
  dim3 gGemm(mt * 8, 2);                    // grid.x divisible by 8 (XCD swizzle)
  dim3 gPrep(gE, 2);
  dim3 gAgg(NGRAPH, CHUNKS, 2);
  dim3 gFc(NGRAPH, 2);

  k_init_cnt<<<209, T, 0, stream>>>((float4*)pool1, (float4*)pool2, deg1, deg2,
                                    batch1, batch2, cnt1, gstart1, cnt2, gstart2, N);
  k_prep<<<gPrep, T, 0, stream>>>(ei1, ei2, deg1, deg2, E);
  k_scan<<<2, SCAN_T, 0, stream>>>(deg1, deg2, off1, off2, cur1, cur2, dinv1, dinv2, N);
  k_fill<<<gPrep, T, 0, stream>>>(ei1, ei2, cur1, cur2, dinv1, dinv2,
                                  adjsrc1, adjsrc2, adjw1, adjw2, E, N);
  k_cast<<<2 * nxb + 512, T, 0, stream>>>((const float4*)x1, (const float4*)x2,
                                          conv1_W, conv2_W,
                                          (ushort4*)xbf1, (ushort4*)xbf2, Wt1, Wt2,
                                          n4, nxb);
  k_gemm_bf16<<<gGemm, 256, 0, stream>>>(xbf1, xbf2, Wt1, Wt2, hbf1, hbf2, N);
  k_aggpool<<<gAgg, 256, 0, stream>>>(hbf1, hbf2, off1, off2, adjsrc1, adjsrc2,
                                      adjw1, adjw2, conv1_b, conv2_b,
                                      cnt1, cnt2, gstart1, gstart2, pool1, pool2);
  k_fc<<<gFc, DDIM, 0, stream>>>(pool1, pool2, fc1_W, fc2_W, fc1_b, fc2_b, fco1, fco2);
  k_final<<<NGRAPH, DDIM, 0, stream>>>(fco1, fco2, final_W, final_b, out);
}